// Round 14
// baseline (928.681 us; speedup 1.0000x reference)
//
#include <hip/hip_runtime.h>

#define WIDTH 1024
#define MBSZ 16
#define LLL 2048
#define NCHUNK 128

typedef __attribute__((ext_vector_type(4))) float f32x4;
typedef __attribute__((ext_vector_type(2))) float f32x2;
typedef __attribute__((ext_vector_type(8))) short short8;
typedef __attribute__((ext_vector_type(4))) short short4v;
typedef __attribute__((ext_vector_type(2))) unsigned u32x2;
typedef __attribute__((ext_vector_type(4))) unsigned u32x4;

#define MFMA16(a, b, c) __builtin_amdgcn_mfma_f32_16x16x32_bf16((a), (b), (c), 0, 0, 0)

__device__ __forceinline__ short f2bf(float f) {
  unsigned u = __float_as_uint(f);
  u = (u + 0x7FFFu + ((u >> 16) & 1u)) >> 16;  // RNE f32->bf16
  return (short)u;
}
__device__ __forceinline__ float bf2f(short s) {
  return __uint_as_float(((unsigned)(unsigned short)s) << 16);
}
__device__ __forceinline__ unsigned cvt_pk(float lo, float hi) {
  unsigned r;
  asm("v_cvt_pk_bf16_f32 %0, %1, %2" : "=v"(r) : "v"(lo), "v"(hi));
  return r;
}
__device__ __forceinline__ float fast_e2u(float x) {
  return __builtin_amdgcn_exp2f(x * (2.30220776f + 0.10294322f * x * x));
}
__device__ __forceinline__ float gelu_f(float x) {
  float e = fast_e2u(x);
  return x * (1.0f - __builtin_amdgcn_rcpf(e + 1.0f));
}
__device__ __forceinline__ float gelu_bwd_f(float x) {
  float e = fast_e2u(x);
  float r = __builtin_amdgcn_rcpf(e + 1.0f);
  return 2.0f * x * r * (1.0f - r) * (0.79788456f + 0.1070322243f * x * x) + (1.0f - r);
}
__device__ __forceinline__ int w2row(int d) { return d * 264 + (d >> 3) * 24; }

// ---------------- 64x128 GEMM tile body
template <int OUTBF>
__device__ __forceinline__ void gemm_64x128(const short* __restrict__ A,
                                            const short* __restrict__ W,
                                            float* __restrict__ C,
                                            short* __restrict__ Cb,
                                            int m0, int n0,
                                            short* sA, short* sB, int t2) {
  const int wv = t2 >> 6, ln = t2 & 63;
  const int fr = ln & 15, kh = (ln >> 4) * 8;
  const int arow = t2 >> 2, aseg = (t2 & 3) * 8;
  f32x4 acc[8];
#pragma unroll
  for (int s = 0; s < 8; ++s) acc[s] = (f32x4){0.f, 0.f, 0.f, 0.f};
  const short* ga = A + (long)(m0 + arow) * 1024 + aseg;
  const short* gw0 = W + (long)(n0 + arow) * 1024 + aseg;
  const short* gw1 = W + (long)(n0 + 64 + arow) * 1024 + aseg;
  for (int k0 = 0; k0 < 1024; k0 += 32) {
    const short8 a8 = *(const short8*)(ga + k0);
    const short8 w80 = *(const short8*)(gw0 + k0);
    const short8 w81 = *(const short8*)(gw1 + k0);
    *(short8*)&sA[arow * 40 + aseg] = a8;
    *(short8*)&sB[arow * 40 + aseg] = w80;
    *(short8*)&sB[(arow + 64) * 40 + aseg] = w81;
    __syncthreads();
    const short8 af = *(const short8*)&sA[(wv * 16 + fr) * 40 + kh];
#pragma unroll
    for (int s = 0; s < 8; ++s) {
      const short8 bf8 = *(const short8*)&sB[(s * 16 + fr) * 40 + kh];
      acc[s] = MFMA16(af, bf8, acc[s]);
    }
    __syncthreads();
  }
  const int orow = m0 + wv * 16 + (ln >> 4) * 4;
#pragma unroll
  for (int s = 0; s < 8; ++s)
#pragma unroll
    for (int q = 0; q < 4; ++q) {
      const long off = (long)(orow + q) * 1024 + n0 + s * 16 + fr;
      if (OUTBF) Cb[off] = f2bf(acc[s][q]);
      else C[off] = acc[s][q];
    }
}

// ---------------- one-shot fp32 -> bf16 conversion
__global__ __launch_bounds__(256) void cvt_kernel(const float* __restrict__ hs,
                                                  const float* __restrict__ Wq,
                                                  const float* __restrict__ Wk,
                                                  const float* __restrict__ Wv,
                                                  const float* __restrict__ Wg,
                                                  const float* __restrict__ Wo,
                                                  short* __restrict__ dst) {
  const long idx = ((long)blockIdx.x * 256 + threadIdx.x) * 8;
  if (idx >= 13631488L) return;
  const float* src;
  long off;
  if (idx < 8388608L)       { src = hs; off = idx; }
  else if (idx < 9437184L)  { src = Wq; off = idx - 8388608L; }
  else if (idx < 10485760L) { src = Wk; off = idx - 9437184L; }
  else if (idx < 11534336L) { src = Wv; off = idx - 10485760L; }
  else if (idx < 12582912L) { src = Wg; off = idx - 11534336L; }
  else                      { src = Wo; off = idx - 12582912L; }
  const f32x4 a = *(const f32x4*)(src + off);
  const f32x4 b = *(const f32x4*)(src + off + 4);
  u32x4 o;
  o[0] = cvt_pk(a[0], a[1]); o[1] = cvt_pk(a[2], a[3]);
  o[2] = cvt_pk(b[0], b[1]); o[3] = cvt_pk(b[2], b[3]);
  *(u32x4*)(dst + idx) = o;
}

// ---------------- final GEMM
__global__ __launch_bounds__(256) void gemm_final(const short* __restrict__ A,
                                                  const short* __restrict__ W,
                                                  float* __restrict__ C) {
  __shared__ __align__(16) short sA[2560];
  __shared__ __align__(16) short sB[5120];
  gemm_64x128<0>(A, W, C, nullptr, blockIdx.x * 64, blockIdx.y * 128, sA, sB, threadIdx.x);
}

// ---------------- fused Q/K/V GEMMs (64x128) + lr
__global__ __launch_bounds__(256) void qkv_lr_kernel(const short* __restrict__ hsb,
                                                     const short* __restrict__ Wqb,
                                                     const short* __restrict__ Wkb,
                                                     const short* __restrict__ Wvb,
                                                     float* __restrict__ Qb,
                                                     float* __restrict__ Kb,
                                                     float* __restrict__ Vb,
                                                     const float* __restrict__ hs,
                                                     const float* __restrict__ lrw,
                                                     const float* __restrict__ lrb,
                                                     float* __restrict__ LRb) {
  __shared__ __align__(16) short sA[2560];
  __shared__ __align__(16) short sB[5120];
  __shared__ __align__(16) float row[1024];
  const int tid = threadIdx.x;
  const int idx = blockIdx.x;
  if (idx < 3072) {
    const int which = idx >> 10, t = idx & 1023;
    const short* W = (which == 0) ? Wqb : (which == 1) ? Wkb : Wvb;
    float* C = (which == 0) ? Qb : (which == 1) ? Kb : Vb;
    gemm_64x128<0>(hsb, W, C, nullptr, (t & 127) * 64, (t >> 7) * 128, sA, sB, tid);
  } else {
    const int t = idx - 3072;
    *(f32x4*)&row[tid * 4] = *(const f32x4*)&hs[(long)t * 1024 + tid * 4];
    __syncthreads();
    const int hh = tid >> 4, j = tid & 15;
    const float* wrow = lrw + hh * 1024;
    float s = 0.f;
#pragma unroll 4
    for (int m = 0; m < 16; ++m) {
      const int c = j * 4 + m * 64;
      f32x4 x = *(const f32x4*)&row[c];
      f32x4 w = *(const f32x4*)&wrow[c];
      s += x[0] * w[0] + x[1] * w[1] + x[2] * w[2] + x[3] * w[3];
    }
#pragma unroll
    for (int o = 8; o; o >>= 1) s += __shfl_xor(s, o, 16);
    if (j == 0) {
      const float v = s + lrb[hh];
      const float sg = 1.f / (1.f + expf(-v));
      const int b = t >> 11, tr = t & 2047;
      LRb[((b << 4) + hh) * 2048 + tr] = sg * (1.f / 64.f);
    }
  }
}

// ---------------- fused scan (blocks 0-63; 8 barriers/chunk, dbuf inputs) + gate GEMM
__global__ __launch_bounds__(512, 2) void scan_gate_kernel(
    float* __restrict__ Qb, const float* __restrict__ Kb, const float* __restrict__ Vb,
    const float* __restrict__ LRb, const float* __restrict__ lti,
    const float* __restrict__ nw, const float* __restrict__ nb,
    const float* __restrict__ W1in, const float* __restrict__ b1in,
    const float* __restrict__ W2in, const float* __restrict__ b2in,
    const short* __restrict__ hsA, const short* __restrict__ Wgb,
    short* __restrict__ Gout) {
  __shared__ __align__(16) short sW1b[256 * 72];
  __shared__ __align__(16) short sW2dp[64 * 264 + 192];
  __shared__ __align__(16) short la1T[64 * 24];
  __shared__ __align__(16) short la2T[256 * 24];
  __shared__ __align__(16) short sX1b[2][16 * 72];
  __shared__ __align__(16) short sXQb[2][16 * 72];
  __shared__ __align__(16) float sXQf[2][16 * 68];
  __shared__ __align__(16) float sTg[2][16 * 72];
  __shared__ __align__(16) short sX2b[16 * 264];
  __shared__ __align__(16) short sXbb[16 * 264];
  __shared__ __align__(16) short sG1c[256 * 24];
  __shared__ __align__(16) short sG2b[16 * 72];
  __shared__ __align__(16) short sG2c[64 * 24];
  __shared__ __align__(16) float sZ2f[16 * 68];
  __shared__ __align__(16) short sC1b[16 * 24];
  __shared__ __align__(16) short sC2b[16 * 24];
  __shared__ __align__(16) float sB1[256];
  __shared__ __align__(16) float sB2[64];
  __shared__ float sLr2[2][16];
  __shared__ float sTok[16];
  __shared__ __align__(16) float sLnw[64];
  __shared__ __align__(16) float sLnb[64];

  const int tid = threadIdx.x;

  if (blockIdx.x >= 64) {
    // gate GEMM: two 256-thread halves, LDS carved from sW1b
    const int hh = tid >> 8, t2 = tid & 255;
    const int tile = (blockIdx.x - 64) * 2 + hh;
    short* sAh = sW1b + hh * 7680;
    short* sBh = sAh + 2560;
    gemm_64x128<1>(hsA, Wgb, nullptr, Gout, (tile & 127) * 64, (tile >> 7) * 128, sAh, sBh, t2);
    return;
  }

  // ---- scan path
  const int bh = blockIdx.x, b = bh >> 4, h = bh & 15;
  const int w = tid >> 6, ln = tid & 63;
  const int fr = ln & 15, half = ln >> 4, hk = half * 8;
  const int nt0 = 2 * w;

  float w1m[8][4], w2m[8][4];
#pragma unroll
  for (int r = 0; r < 8; ++r) {
    const int T = w * 8 + r, dt = T >> 4, pt = T & 15;
#pragma unroll
    for (int qq = 0; qq < 4; ++qq) {
      w1m[r][qq] = W1in[h * 16384 + (dt * 16 + half * 4 + qq) * 256 + pt * 16 + fr];
      w2m[r][qq] = W2in[h * 16384 + (pt * 16 + half * 4 + qq) * 64 + dt * 16 + fr];
    }
  }
  for (int e = tid; e < 16384; e += 512) {
    {
      const int d = e >> 8, p = e & 255;
      sW1b[p * 72 + d] = f2bf(W1in[h * 16384 + e]);
    }
    {
      const int p = e >> 6, d = e & 63;
      sW2dp[w2row(d) + (p ^ (((d >> 3) & 3) << 3))] = f2bf(W2in[h * 16384 + e]);
    }
  }
  if (tid < 256) sB1[tid] = b1in[h * 256 + tid];
  if (tid < 64) { sB2[tid] = b2in[h * 64 + tid]; sLnw[tid] = nw[h * 64 + tid]; sLnb[tid] = nb[h * 64 + tid]; }
  if (tid < 16) sTok[tid] = fmaxf(1.0f / (float)(tid + 1) + lti[tid], 0.0f);

  const f32x4 zf4 = (f32x4){0.f, 0.f, 0.f, 0.f};
  short8 zs8;
#pragma unroll
  for (int j = 0; j < 8; ++j) zs8[j] = 0;

  // chunk-input prefetch: tid>=256 own it (f32x4 each; 16 rows x 4 threads)
  const int ct = tid - 256;
  const int ci = ct >> 4;
  const int cd = (ct & 15) * 4;
  f32x4 pk4, pq4, pv4;
  float plr = 0.f;
  if (tid >= 256) {
    const long a0 = ((long)(b * LLL + ci)) * WIDTH + h * 64 + cd;
    pk4 = *(const f32x4*)&Kb[a0];
    pq4 = *(const f32x4*)&Qb[a0];
    pv4 = *(const f32x4*)&Vb[a0];
    if (ct < 16) plr = LRb[(long)bh * 2048 + ct];
    // commit chunk 0 -> buffer 0
    *(u32x2*)&sX1b[0][ci * 72 + cd] = (u32x2){cvt_pk(pk4[0], pk4[1]), cvt_pk(pk4[2], pk4[3])};
    *(u32x2*)&sXQb[0][ci * 72 + cd] = (u32x2){cvt_pk(pq4[0], pq4[1]), cvt_pk(pq4[2], pq4[3])};
    *(f32x4*)&sXQf[0][ci * 68 + cd] = pq4;
    f32x4 tg4;
#pragma unroll
    for (int e = 0; e < 4; ++e) tg4[e] = pv4[e] - pk4[e];
    *(f32x4*)&sTg[0][ci * 72 + cd] = tg4;
    if (ct < 16) sLr2[0][ct] = plr;
  }
  __syncthreads();

  for (int n = 0; n < NCHUNK; ++n) {
    const int cb = n & 1;
    const long gbase = ((long)(b * LLL + n * MBSZ)) * WIDTH + h * 64;

    // ---- B: Z1 & XQ@W1 -> z1/q1; X2->LDS; la1T; C1 (wave 0)
    short8 aX1[2], aXQ[2];
    aX1[0] = *(const short8*)&sX1b[cb][fr * 72 + hk];
    aX1[1] = *(const short8*)&sX1b[cb][fr * 72 + 32 + hk];
    aXQ[0] = *(const short8*)&sXQb[cb][fr * 72 + hk];
    aXQ[1] = *(const short8*)&sXQb[cb][fr * 72 + 32 + hk];
    f32x4 z1[2], q1[2];
    float b1p[2];
#pragma unroll
    for (int t = 0; t < 2; ++t) {
      const int p = (nt0 + t) * 16 + fr;
      z1[t] = zf4; q1[t] = zf4;
#pragma unroll
      for (int ks = 0; ks < 2; ++ks) {
        short8 bw = *(const short8*)&sW1b[p * 72 + ks * 32 + hk];
        z1[t] = MFMA16(aX1[ks], bw, z1[t]);
        q1[t] = MFMA16(aXQ[ks], bw, q1[t]);
      }
      b1p[t] = sB1[p];
#pragma unroll
      for (int qq = 0; qq < 4; ++qq) {
        z1[t][qq] += b1p[t];
        sX2b[(half * 4 + qq) * 264 + p] = f2bf(gelu_f(z1[t][qq]));
      }
    }
    {
      const float tok15 = sTok[15];
      const int d = tid >> 3, j0 = (tid & 7) * 2;
      const float v0 = bf2f(sX1b[cb][j0 * 72 + d]) * (tok15 * sLr2[cb][j0]);
      const float v1 = bf2f(sX1b[cb][(j0 + 1) * 72 + d]) * (tok15 * sLr2[cb][j0 + 1]);
      *(unsigned*)&la1T[d * 24 + j0] = cvt_pk(v0, v1);
    }
    if (w == 0) {
      f32x4 c = MFMA16(aXQ[0], aX1[0], zf4);
      c = MFMA16(aXQ[1], aX1[1], c);
#pragma unroll
      for (int qq = 0; qq < 4; ++qq) {
        const int i = half * 4 + qq, j = fr;
        sC1b[i * 24 + j] = f2bf((i >= j) ? sTok[i] * sLr2[cb][j] * (c[qq] + 1.0f) : 0.0f);
      }
    }
    __syncthreads();  // B

    // ---- C: Z2 = X2@W2 + b2 (waves 0-3)
    float bb2old = 0.f;
    if (w < 4) {
      const int d = w * 16 + fr;
      const int sw = ((d >> 3) & 3) << 3;
      const int rb = w2row(d);
      f32x4 za = zf4, zb = zf4;
#pragma unroll
      for (int ks = 0; ks < 4; ++ks) {
        short8 a = *(const short8*)&sX2b[fr * 264 + ks * 32 + hk];
        short8 bfr = *(const short8*)&sW2dp[rb + ((ks * 32 + hk) ^ sw)];
        za = MFMA16(a, bfr, za);
      }
#pragma unroll
      for (int ks = 4; ks < 8; ++ks) {
        short8 a = *(const short8*)&sX2b[fr * 264 + ks * 32 + hk];
        short8 bfr = *(const short8*)&sW2dp[rb + ((ks * 32 + hk) ^ sw)];
        zb = MFMA16(a, bfr, zb);
      }
      bb2old = sB2[d];
#pragma unroll
      for (int qq = 0; qq < 4; ++qq)
        sZ2f[(half * 4 + qq) * 68 + d] = za[qq] + zb[qq] + bb2old;
    }
    __syncthreads();  // C

    // ---- D: gZ2 = ln_l2_bwd(Z2, V-K) (tid<256) | la2T (tid>=256)
    if (tid < 256) {
      const int i = tid >> 4, j4 = tid & 15;
      const f32x4 z = *(const f32x4*)&sZ2f[i * 68 + j4 * 4];
      float s1 = z[0] + z[1] + z[2] + z[3];
      float s2 = z[0] * z[0] + z[1] * z[1] + z[2] * z[2] + z[3] * z[3];
#pragma unroll
      for (int o = 8; o; o >>= 1) { s1 += __shfl_xor(s1, o, 16); s2 += __shfl_xor(s2, o, 16); }
      const float mu = s1 * (1.f / 64.f);
      const float rstd = rsqrtf(s2 * (1.f / 64.f) - mu * mu + 1e-6f);
      const f32x4 g = *(const f32x4*)&sLnw[j4 * 4];
      const f32x4 bb = *(const f32x4*)&sLnb[j4 * 4];
      const f32x4 tg = *(const f32x4*)&sTg[cb][i * 72 + j4 * 4];
      f32x4 xh, gx;
      float a1 = 0.f, a2 = 0.f;
#pragma unroll
      for (int e = 0; e < 4; ++e) {
        xh[e] = (z[e] - mu) * rstd;
        gx[e] = (g[e] * xh[e] + bb[e] - tg[e]) * g[e];
        a1 += gx[e]; a2 += gx[e] * xh[e];
      }
#pragma unroll
      for (int o = 8; o; o >>= 1) { a1 += __shfl_xor(a1, o, 16); a2 += __shfl_xor(a2, o, 16); }
      const float m1 = a1 * (1.f / 64.f), m2 = a2 * (1.f / 64.f);
      float o4[4];
#pragma unroll
      for (int e = 0; e < 4; ++e) o4[e] = (gx[e] - m1 - xh[e] * m2) * rstd;
      const unsigned lo = cvt_pk(o4[0], o4[1]);
      const unsigned hi = cvt_pk(o4[2], o4[3]);
      *(u32x2*)&sG2b[i * 72 + j4 * 4] = (u32x2){lo, hi};
      sG2c[(j4 * 4 + 0) * 24 + i] = (short)lo;
      sG2c[(j4 * 4 + 1) * 24 + i] = (short)(lo >> 16);
      sG2c[(j4 * 4 + 2) * 24 + i] = (short)hi;
      sG2c[(j4 * 4 + 3) * 24 + i] = (short)(hi >> 16);
    } else {
      const int pp = tid - 256;
      const float tok15 = sTok[15];
      unsigned uu[8];
#pragma unroll
      for (int jp = 0; jp < 8; ++jp) {
        const float v0 = bf2f(sX2b[(2 * jp) * 264 + pp]) * (tok15 * sLr2[cb][2 * jp]);
        const float v1 = bf2f(sX2b[(2 * jp + 1) * 264 + pp]) * (tok15 * sLr2[cb][2 * jp + 1]);
        uu[jp] = cvt_pk(v0, v1);
      }
      *(u32x4*)&la2T[pp * 24] = (u32x4){uu[0], uu[1], uu[2], uu[3]};
      *(u32x4*)&la2T[pp * 24 + 8] = (u32x4){uu[4], uu[5], uu[6], uu[7]};
    }
    __syncthreads();  // D

    // ---- E: gZ1 -> sG1c; X2_bar (same-wave sG1c) -> sXbb; b2 update (tid<64)
    {
      short8 aG2[2];
      aG2[0] = *(const short8*)&sG2b[fr * 72 + hk];
      aG2[1] = *(const short8*)&sG2b[fr * 72 + 32 + hk];
#pragma unroll
      for (int t = 0; t < 2; ++t) {
        const int p = (nt0 + t) * 16 + fr;
        f32x4 g = zf4;
#pragma unroll
        for (int ks = 0; ks < 2; ++ks) {
          const int dg = ks * 32 + hk;
          const int rb2 = w2row(dg) + (p ^ (((dg >> 3) & 3) << 3));
          short8 bw;
#pragma unroll
          for (int jj = 0; jj < 8; ++jj) bw[jj] = sW2dp[rb2 + jj * 264];
          g = MFMA16(aG2[ks], bw, g);
        }
        const unsigned lo = cvt_pk(g[0] * gelu_bwd_f(z1[t][0]), g[1] * gelu_bwd_f(z1[t][1]));
        const unsigned hi = cvt_pk(g[2] * gelu_bwd_f(z1[t][2]), g[3] * gelu_bwd_f(z1[t][3]));
        *(u32x2*)&sG1c[p * 24 + half * 4] = (u32x2){lo, hi};
      }
    }
    {
      short8 ac = zs8;
      if (half < 2) ac = *(const short8*)&sC1b[fr * 24 + hk];
#pragma unroll
      for (int t = 0; t < 2; ++t) {
        const int p = (nt0 + t) * 16 + fr;
        short8 bg = zs8;
        if (half < 2) bg = *(const short8*)&sG1c[p * 24 + hk];  // own-wave writes
        f32x4 corr = MFMA16(ac, bg, zf4);
#pragma unroll
        for (int qq = 0; qq < 4; ++qq)
          sXbb[(half * 4 + qq) * 264 + p] = f2bf(gelu_f(q1[t][qq] + b1p[t] - corr[qq]));
      }
    }
    if (tid < 64) {
      float s = 0.f;
#pragma unroll
      for (int k = 0; k < 4; ++k) {
        const short4v g4 = *(const short4v*)&sG2c[tid * 24 + k * 4];
        const f32x4 lr4 = *(const f32x4*)&sLr2[cb][k * 4];
        s += lr4[0] * bf2f(g4[0]) + lr4[1] * bf2f(g4[1]) +
             lr4[2] * bf2f(g4[2]) + lr4[3] * bf2f(g4[3]);
      }
      sB2[tid] -= sTok[15] * s;
    }
    __syncthreads();  // E

    // ---- F: W1 reg-update | b1 update (tid<256)
    {
#pragma unroll
      for (int r = 0; r < 8; ++r) {
        const int T = w * 8 + r, dt = T >> 4, pt = T & 15;
        short8 af = zs8, bg = zs8;
        if (half < 2) {
          af = *(const short8*)&la1T[(dt * 16 + fr) * 24 + hk];
          bg = *(const short8*)&sG1c[(pt * 16 + fr) * 24 + hk];
        }
        f32x4 dl = MFMA16(af, bg, zf4);
        const int pp = pt * 16 + fr, d0 = dt * 16 + half * 4;
        w1m[r][0] -= dl[0]; w1m[r][1] -= dl[1]; w1m[r][2] -= dl[2]; w1m[r][3] -= dl[3];
        const unsigned lo = cvt_pk(w1m[r][0], w1m[r][1]);
        const unsigned hi = cvt_pk(w1m[r][2], w1m[r][3]);
        *(u32x2*)&sW1b[pp * 72 + d0] = (u32x2){lo, hi};
      }
    }
    if (tid < 256) {
      float s = 0.f;
#pragma unroll
      for (int k = 0; k < 4; ++k) {
        const short4v g4 = *(const short4v*)&sG1c[tid * 24 + k * 4];
        const f32x4 lr4 = *(const f32x4*)&sLr2[cb][k * 4];
        s += lr4[0] * bf2f(g4[0]) + lr4[1] * bf2f(g4[1]) +
             lr4[2] * bf2f(g4[2]) + lr4[3] * bf2f(g4[3]);
      }
      sB1[tid] -= sTok[15] * s;
    }
    __syncthreads();  // F

    // ---- G: prefetch issue (tid>=256) | Z2bar partial (w0-3) | C2 (w4)
    if (tid >= 256) {
      const int nn = (n + 1 < NCHUNK) ? n + 1 : n;
      const long a1 = ((long)(b * LLL + nn * MBSZ + ci)) * WIDTH + h * 64 + cd;
      pk4 = *(const f32x4*)&Kb[a1];
      pq4 = *(const f32x4*)&Qb[a1];
      pv4 = *(const f32x4*)&Vb[a1];
      if (ct < 16) plr = LRb[(long)bh * 2048 + nn * MBSZ + ct];
    }
    f32x4 zbar = zf4;
    if (w < 4) {
      const int d = w * 16 + fr;
      const int sw = ((d >> 3) & 3) << 3;
      const int rb = w2row(d);
      f32x4 za = zf4, zb = zf4;
#pragma unroll
      for (int ks = 0; ks < 4; ++ks) {
        short8 a = *(const short8*)&sXbb[fr * 264 + ks * 32 + hk];
        short8 bfr = *(const short8*)&sW2dp[rb + ((ks * 32 + hk) ^ sw)];
        za = MFMA16(a, bfr, za);
      }
#pragma unroll
      for (int ks = 4; ks < 8; ++ks) {
        short8 a = *(const short8*)&sXbb[fr * 264 + ks * 32 + hk];
        short8 bfr = *(const short8*)&sW2dp[rb + ((ks * 32 + hk) ^ sw)];
        zb = MFMA16(a, bfr, zb);
      }
      zbar[0] = za[0] + zb[0]; zbar[1] = za[1] + zb[1];
      zbar[2] = za[2] + zb[2]; zbar[3] = za[3] + zb[3];
    } else if (w == 4) {
      f32x4 c = zf4;
#pragma unroll
      for (int ks = 0; ks < 8; ++ks) {
        short8 a = *(const short8*)&sXbb[fr * 264 + ks * 32 + hk];
        short8 bx = *(const short8*)&sX2b[fr * 264 + ks * 32 + hk];
        c = MFMA16(a, bx, c);
      }
#pragma unroll
      for (int qq = 0; qq < 4; ++qq) {
        const int i = half * 4 + qq, j = fr;
        sC2b[i * 24 + j] = f2bf((i >= j) ? sTok[i] * sLr2[cb][j] * (c[qq] + 1.0f) : 0.0f);
      }
    }
    __syncthreads();  // G

    // ---- H: Z2bar finalize (w0-3) + W2 reg-update (all)
    if (w < 4) {
      const int d = w * 16 + fr;
      short8 ac = zs8, bg = zs8;
      if (half < 2) {
        ac = *(const short8*)&sC2b[fr * 24 + hk];
        bg = *(const short8*)&sG2c[d * 24 + hk];
      }
      f32x4 corr = MFMA16(ac, bg, zf4);
#pragma unroll
      for (int qq = 0; qq < 4; ++qq)
        sZ2f[(half * 4 + qq) * 68 + d] = zbar[qq] + bb2old - corr[qq];
    }
    {
#pragma unroll
      for (int r = 0; r < 8; ++r) {
        const int T = w * 8 + r, pt = T & 15, dt = T >> 4;
        short8 af = zs8, bg = zs8;
        if (half < 2) {
          af = *(const short8*)&la2T[(pt * 16 + fr) * 24 + hk];
          bg = *(const short8*)&sG2c[(dt * 16 + fr) * 24 + hk];
        }
        f32x4 dl = MFMA16(af, bg, zf4);
        const int dd = dt * 16 + fr;
        const int swp = ((dd >> 3) & 3) << 3;
        const int p0 = pt * 16 + half * 4;
        w2m[r][0] -= dl[0]; w2m[r][1] -= dl[1]; w2m[r][2] -= dl[2]; w2m[r][3] -= dl[3];
        const unsigned lo = cvt_pk(w2m[r][0], w2m[r][1]);
        const unsigned hi = cvt_pk(w2m[r][2], w2m[r][3]);
        *(u32x2*)&sW2dp[w2row(dd) + (p0 ^ swp)] = (u32x2){lo, hi};
      }
    }
    __syncthreads();  // H

    // ---- I: out-LN -> Qb (tid<256) | commit next chunk -> buffers cb^1 (tid>=256)
    if (tid < 256) {
      const int i = tid >> 4, j4 = tid & 15;
      const f32x4 z = *(const f32x4*)&sZ2f[i * 68 + j4 * 4];
      float s1 = z[0] + z[1] + z[2] + z[3];
      float s2 = z[0] * z[0] + z[1] * z[1] + z[2] * z[2] + z[3] * z[3];
#pragma unroll
      for (int o = 8; o; o >>= 1) { s1 += __shfl_xor(s1, o, 16); s2 += __shfl_xor(s2, o, 16); }
      const float mu = s1 * (1.f / 64.f);
      const float rstd = rsqrtf(s2 * (1.f / 64.f) - mu * mu + 1e-6f);
      const f32x4 g = *(const f32x4*)&sLnw[j4 * 4];
      const f32x4 bb = *(const f32x4*)&sLnb[j4 * 4];
      const f32x4 xq = *(const f32x4*)&sXQf[cb][i * 68 + j4 * 4];
      f32x4 o4;
#pragma unroll
      for (int e = 0; e < 4; ++e) o4[e] = xq[e] + g[e] * ((z[e] - mu) * rstd) + bb[e];
      *(f32x4*)&Qb[gbase + (long)i * WIDTH + j4 * 4] = o4;
    } else {
      const int nb2 = cb ^ 1;
      *(u32x2*)&sX1b[nb2][ci * 72 + cd] = (u32x2){cvt_pk(pk4[0], pk4[1]), cvt_pk(pk4[2], pk4[3])};
      *(u32x2*)&sXQb[nb2][ci * 72 + cd] = (u32x2){cvt_pk(pq4[0], pq4[1]), cvt_pk(pq4[2], pq4[3])};
      *(f32x4*)&sXQf[nb2][ci * 68 + cd] = pq4;
      f32x4 tg4;
#pragma unroll
      for (int e = 0; e < 4; ++e) tg4[e] = pv4[e] - pk4[e];
      *(f32x4*)&sTg[nb2][ci * 72 + cd] = tg4;
      if (ct < 16) sLr2[nb2][ct] = plr;
    }
    __syncthreads();  // I
  }
}

// ---------------- epilogue: T(bf16) = gelu(G_bf16) * ln_fwd(XQW_f32, post_w, post_b)
__global__ __launch_bounds__(256) void epi_kernel(const float* __restrict__ X,
                                                  const short* __restrict__ G,
                                                  const float* __restrict__ pw,
                                                  const float* __restrict__ pb,
                                                  short* __restrict__ T) {
  __shared__ float red[8];
  const int t = blockIdx.x, tid = threadIdx.x;
  const long base = (long)t * 1024 + tid * 4;
  f32x4 x = *(const f32x4*)&X[base];
  float s1 = x[0] + x[1] + x[2] + x[3];
  float s2 = x[0] * x[0] + x[1] * x[1] + x[2] * x[2] + x[3] * x[3];
#pragma unroll
  for (int o = 32; o; o >>= 1) { s1 += __shfl_xor(s1, o, 64); s2 += __shfl_xor(s2, o, 64); }
  const int wv = tid >> 6, ln = tid & 63;
  if (ln == 0) { red[wv] = s1; red[4 + wv] = s2; }
  __syncthreads();
  s1 = red[0] + red[1] + red[2] + red[3];
  s2 = red[4] + red[5] + red[6] + red[7];
  const float mu = s1 * (1.f / 1024.f);
  const float rstd = rsqrtf(s2 * (1.f / 1024.f) - mu * mu + 1e-6f);
  const short4v g4 = *(const short4v*)&G[base];
  f32x4 w = *(const f32x4*)&pw[tid * 4];
  f32x4 bb = *(const f32x4*)&pb[tid * 4];
  float o4[4];
#pragma unroll
  for (int e = 0; e < 4; ++e) {
    float y = w[e] * ((x[e] - mu) * rstd) + bb[e];
    o4[e] = gelu_f(bf2f(g4[e])) * y;
  }
  *(u32x2*)&T[base] = (u32x2){cvt_pk(o4[0], o4[1]), cvt_pk(o4[2], o4[3])};
}

extern "C" void kernel_launch(void* const* d_in, const int* in_sizes, int n_in,
                              void* d_out, int out_size, void* d_ws, size_t ws_size,
                              hipStream_t stream) {
  const float* hs  = (const float*)d_in[0];
  const float* Wq  = (const float*)d_in[1];
  const float* Wk  = (const float*)d_in[2];
  const float* Wv  = (const float*)d_in[3];
  const float* Wo  = (const float*)d_in[4];
  const float* Wg  = (const float*)d_in[5];
  const float* lrw = (const float*)d_in[6];
  const float* lrb = (const float*)d_in[7];
  const float* lti = (const float*)d_in[8];
  const float* nw  = (const float*)d_in[9];
  const float* nb  = (const float*)d_in[10];
  const float* W1  = (const float*)d_in[11];
  const float* b1  = (const float*)d_in[12];
  const float* W2  = (const float*)d_in[13];
  const float* b2  = (const float*)d_in[14];
  const float* pw  = (const float*)d_in[15];
  const float* pb  = (const float*)d_in[16];
  float* out = (float*)d_out;
  float* ws = (float*)d_ws;

  float* Qb  = ws;
  float* Kb  = ws + 8388608;
  float* Vb  = ws + 16777216;
  float* LRb = ws + 25165824;
  short* hsb = (short*)(ws + 25296896);
  short* Wqb = hsb + 8388608;
  short* Wkb = Wqb + 1048576;
  short* Wvb = Wkb + 1048576;
  short* Wgb = Wvb + 1048576;
  short* Wob = Wgb + 1048576;
  short* Tb  = (short*)Kb;
  short* Gbb = (short*)out;

  cvt_kernel<<<6656, 256, 0, stream>>>(hs, Wq, Wk, Wv, Wg, Wo, hsb);
  qkv_lr_kernel<<<11264, 256, 0, stream>>>(hsb, Wqb, Wkb, Wvb, Qb, Kb, Vb, hs, lrw, lrb, LRb);
  scan_gate_kernel<<<576, 512, 0, stream>>>(Qb, Kb, Vb, LRb, lti, nw, nb, W1, b1, W2, b2,
                                            hsb, Wgb, Gbb);
  epi_kernel<<<8192, 256, 0, stream>>>(Qb, Gbb, pw, pb, Tb);
  gemm_final<<<dim3(128, 8), 256, 0, stream>>>(Tb, Wob, out);
}

// Round 15
// 916.994 us; speedup vs baseline: 1.0127x; 1.0127x over previous
//
#include <hip/hip_runtime.h>

#define WIDTH 1024
#define MBSZ 16
#define LLL 2048
#define NCHUNK 128

typedef __attribute__((ext_vector_type(4))) float f32x4;
typedef __attribute__((ext_vector_type(2))) float f32x2;
typedef __attribute__((ext_vector_type(8))) short short8;
typedef __attribute__((ext_vector_type(4))) short short4v;
typedef __attribute__((ext_vector_type(2))) unsigned u32x2;
typedef __attribute__((ext_vector_type(4))) unsigned u32x4;

#define MFMA16(a, b, c) __builtin_amdgcn_mfma_f32_16x16x32_bf16((a), (b), (c), 0, 0, 0)

__device__ __forceinline__ short f2bf(float f) {
  unsigned u = __float_as_uint(f);
  u = (u + 0x7FFFu + ((u >> 16) & 1u)) >> 16;  // RNE f32->bf16
  return (short)u;
}
__device__ __forceinline__ float bf2f(short s) {
  return __uint_as_float(((unsigned)(unsigned short)s) << 16);
}
__device__ __forceinline__ unsigned cvt_pk(float lo, float hi) {
  unsigned r;
  asm("v_cvt_pk_bf16_f32 %0, %1, %2" : "=v"(r) : "v"(lo), "v"(hi));
  return r;
}
__device__ __forceinline__ float fast_e2u(float x) {
  return __builtin_amdgcn_exp2f(x * (2.30220776f + 0.10294322f * x * x));
}
__device__ __forceinline__ float gelu_f(float x) {
  float e = fast_e2u(x);
  return x * (1.0f - __builtin_amdgcn_rcpf(e + 1.0f));
}
__device__ __forceinline__ float gelu_bwd_f(float x) {
  float e = fast_e2u(x);
  float r = __builtin_amdgcn_rcpf(e + 1.0f);
  return 2.0f * x * r * (1.0f - r) * (0.79788456f + 0.1070322243f * x * x) + (1.0f - r);
}
__device__ __forceinline__ int w2row(int d) { return d * 264 + (d >> 3) * 24; }

// ---------------- 64x128 GEMM tile body: C[m0..+63][n0..+127] = A @ W^T (bf16 in)
template <int OUTBF>
__device__ __forceinline__ void gemm_64x128(const short* __restrict__ A,
                                            const short* __restrict__ W,
                                            float* __restrict__ C,
                                            short* __restrict__ Cb,
                                            int m0, int n0,
                                            short* sA, short* sB, int t2) {
  const int wv = t2 >> 6, ln = t2 & 63;
  const int fr = ln & 15, kh = (ln >> 4) * 8;
  const int arow = t2 >> 2, aseg = (t2 & 3) * 8;
  f32x4 acc[8];
#pragma unroll
  for (int s = 0; s < 8; ++s) acc[s] = (f32x4){0.f, 0.f, 0.f, 0.f};
  const short* ga = A + (long)(m0 + arow) * 1024 + aseg;
  const short* gw0 = W + (long)(n0 + arow) * 1024 + aseg;
  const short* gw1 = W + (long)(n0 + 64 + arow) * 1024 + aseg;
  for (int k0 = 0; k0 < 1024; k0 += 32) {
    const short8 a8 = *(const short8*)(ga + k0);
    const short8 w80 = *(const short8*)(gw0 + k0);
    const short8 w81 = *(const short8*)(gw1 + k0);
    *(short8*)&sA[arow * 40 + aseg] = a8;
    *(short8*)&sB[arow * 40 + aseg] = w80;
    *(short8*)&sB[(arow + 64) * 40 + aseg] = w81;
    __syncthreads();
    const short8 af = *(const short8*)&sA[(wv * 16 + fr) * 40 + kh];
#pragma unroll
    for (int s = 0; s < 8; ++s) {
      const short8 bf8 = *(const short8*)&sB[(s * 16 + fr) * 40 + kh];
      acc[s] = MFMA16(af, bf8, acc[s]);
    }
    __syncthreads();
  }
  const int orow = m0 + wv * 16 + (ln >> 4) * 4;
#pragma unroll
  for (int s = 0; s < 8; ++s)
#pragma unroll
    for (int q = 0; q < 4; ++q) {
      const long off = (long)(orow + q) * 1024 + n0 + s * 16 + fr;
      if (OUTBF) Cb[off] = f2bf(acc[s][q]);
      else C[off] = acc[s][q];
    }
}

// ---------------- one-shot fp32 -> bf16 conversion
__global__ __launch_bounds__(256) void cvt_kernel(const float* __restrict__ hs,
                                                  const float* __restrict__ Wq,
                                                  const float* __restrict__ Wk,
                                                  const float* __restrict__ Wv,
                                                  const float* __restrict__ Wg,
                                                  const float* __restrict__ Wo,
                                                  short* __restrict__ dst) {
  const long idx = ((long)blockIdx.x * 256 + threadIdx.x) * 8;
  if (idx >= 13631488L) return;
  const float* src;
  long off;
  if (idx < 8388608L)       { src = hs; off = idx; }
  else if (idx < 9437184L)  { src = Wq; off = idx - 8388608L; }
  else if (idx < 10485760L) { src = Wk; off = idx - 9437184L; }
  else if (idx < 11534336L) { src = Wv; off = idx - 10485760L; }
  else if (idx < 12582912L) { src = Wg; off = idx - 11534336L; }
  else                      { src = Wo; off = idx - 12582912L; }
  const f32x4 a = *(const f32x4*)(src + off);
  const f32x4 b = *(const f32x4*)(src + off + 4);
  u32x4 o;
  o[0] = cvt_pk(a[0], a[1]); o[1] = cvt_pk(a[2], a[3]);
  o[2] = cvt_pk(b[0], b[1]); o[3] = cvt_pk(b[2], b[3]);
  *(u32x4*)(dst + idx) = o;
}

// ---------------- final GEMM: out = Tb @ Wob^T (fp32 out), 64x128 tiles
__global__ __launch_bounds__(256) void gemm_final(const short* __restrict__ A,
                                                  const short* __restrict__ W,
                                                  float* __restrict__ C) {
  __shared__ __align__(16) short sA[2560];
  __shared__ __align__(16) short sB[5120];
  gemm_64x128<0>(A, W, C, nullptr, blockIdx.x * 64, blockIdx.y * 128, sA, sB, threadIdx.x);
}

// ---------------- fused Q/K/V GEMMs (64x128) + lr
__global__ __launch_bounds__(256) void qkv_lr_kernel(const short* __restrict__ hsb,
                                                     const short* __restrict__ Wqb,
                                                     const short* __restrict__ Wkb,
                                                     const short* __restrict__ Wvb,
                                                     float* __restrict__ Qb,
                                                     float* __restrict__ Kb,
                                                     float* __restrict__ Vb,
                                                     const float* __restrict__ hs,
                                                     const float* __restrict__ lrw,
                                                     const float* __restrict__ lrb,
                                                     float* __restrict__ LRb) {
  __shared__ __align__(16) short sA[2560];
  __shared__ __align__(16) short sB[5120];
  __shared__ __align__(16) float row[1024];
  const int tid = threadIdx.x;
  const int idx = blockIdx.x;
  if (idx < 3072) {
    const int which = idx >> 10, t = idx & 1023;
    const short* W = (which == 0) ? Wqb : (which == 1) ? Wkb : Wvb;
    float* C = (which == 0) ? Qb : (which == 1) ? Kb : Vb;
    gemm_64x128<0>(hsb, W, C, nullptr, (t & 127) * 64, (t >> 7) * 128, sA, sB, tid);
  } else {
    const int t = idx - 3072;
    *(f32x4*)&row[tid * 4] = *(const f32x4*)&hs[(long)t * 1024 + tid * 4];
    __syncthreads();
    const int hh = tid >> 4, j = tid & 15;
    const float* wrow = lrw + hh * 1024;
    float s = 0.f;
#pragma unroll 4
    for (int m = 0; m < 16; ++m) {
      const int c = j * 4 + m * 64;
      f32x4 x = *(const f32x4*)&row[c];
      f32x4 w = *(const f32x4*)&wrow[c];
      s += x[0] * w[0] + x[1] * w[1] + x[2] * w[2] + x[3] * w[3];
    }
#pragma unroll
    for (int o = 8; o; o >>= 1) s += __shfl_xor(s, o, 16);
    if (j == 0) {
      const float v = s + lrb[hh];
      const float sg = 1.f / (1.f + expf(-v));
      const int b = t >> 11, tr = t & 2047;
      LRb[((b << 4) + hh) * 2048 + tr] = sg * (1.f / 64.f);
    }
  }
}

// ---------------- fused scan (blocks 0-63, R11 structure) + gate GEMM (blocks 64+)
__global__ __launch_bounds__(512, 2) void scan_gate_kernel(
    float* __restrict__ Qb, const float* __restrict__ Kb, const float* __restrict__ Vb,
    const float* __restrict__ LRb, const float* __restrict__ lti,
    const float* __restrict__ nw, const float* __restrict__ nb,
    const float* __restrict__ W1in, const float* __restrict__ b1in,
    const float* __restrict__ W2in, const float* __restrict__ b2in,
    const short* __restrict__ hsA, const short* __restrict__ Wgb,
    short* __restrict__ Gout) {
  __shared__ __align__(16) short sW1b[256 * 72];
  __shared__ __align__(16) short sW2dp[64 * 264 + 192];
  __shared__ __align__(16) short la1T[64 * 24];
  __shared__ __align__(16) short la2T[256 * 24];
  __shared__ __align__(16) short sX1b[16 * 72];
  __shared__ __align__(16) short sXQb[16 * 72];
  __shared__ __align__(16) float sXQf[16 * 68];
  __shared__ __align__(16) float sTg[16 * 72];
  __shared__ __align__(16) short sX2b[16 * 264];
  __shared__ __align__(16) short sXbb[16 * 264];
  __shared__ __align__(16) short sG1c[256 * 24];
  __shared__ __align__(16) short sG2b[16 * 72];
  __shared__ __align__(16) short sG2c[64 * 24];
  __shared__ __align__(16) float sZ2f[16 * 68];
  __shared__ __align__(16) short sC1b[16 * 24];
  __shared__ __align__(16) short sC2b[16 * 24];
  __shared__ __align__(16) float sB1[256];
  __shared__ __align__(16) float sB2[64];
  __shared__ float sLr[16];
  __shared__ float sTok[16];
  __shared__ __align__(16) float sLnw[64];
  __shared__ __align__(16) float sLnb[64];

  const int tid = threadIdx.x;

  if (blockIdx.x >= 64) {
    // gate GEMM: two 256-thread halves, LDS carved from sW1b
    const int hh = tid >> 8, t2 = tid & 255;
    const int tile = (blockIdx.x - 64) * 2 + hh;
    short* sAh = sW1b + hh * 7680;
    short* sBh = sAh + 2560;
    gemm_64x128<1>(hsA, Wgb, nullptr, Gout, (tile & 127) * 64, (tile >> 7) * 128, sAh, sBh, t2);
    return;
  }

  // ---- scan path
  const int bh = blockIdx.x, b = bh >> 4, h = bh & 15;
  const int w = tid >> 6, ln = tid & 63;
  const int fr = ln & 15, half = ln >> 4, hk = half * 8;
  const int nt0 = 2 * w;

  float w1m[8][4], w2m[8][4];
#pragma unroll
  for (int r = 0; r < 8; ++r) {
    const int T = w * 8 + r, dt = T >> 4, pt = T & 15;
#pragma unroll
    for (int qq = 0; qq < 4; ++qq) {
      w1m[r][qq] = W1in[h * 16384 + (dt * 16 + half * 4 + qq) * 256 + pt * 16 + fr];
      w2m[r][qq] = W2in[h * 16384 + (pt * 16 + half * 4 + qq) * 64 + dt * 16 + fr];
    }
  }
  for (int e = tid; e < 16384; e += 512) {
    {
      const int d = e >> 8, p = e & 255;
      sW1b[p * 72 + d] = f2bf(W1in[h * 16384 + e]);
    }
    {
      const int p = e >> 6, d = e & 63;
      sW2dp[w2row(d) + (p ^ (((d >> 3) & 3) << 3))] = f2bf(W2in[h * 16384 + e]);
    }
  }
  if (tid < 256) sB1[tid] = b1in[h * 256 + tid];
  if (tid < 64) { sB2[tid] = b2in[h * 64 + tid]; sLnw[tid] = nw[h * 64 + tid]; sLnb[tid] = nb[h * 64 + tid]; }
  if (tid < 16) sTok[tid] = fmaxf(1.0f / (float)(tid + 1) + lti[tid], 0.0f);

  const f32x4 zf4 = (f32x4){0.f, 0.f, 0.f, 0.f};
  short8 zs8;
#pragma unroll
  for (int j = 0; j < 8; ++j) zs8[j] = 0;

  const int pf_i = tid >> 5;
  const int pf_d = (tid & 31) * 2;
  f32x2 pk, pq, pv;
  float plr = 0.f;
  {
    const long a0 = ((long)(b * LLL + pf_i)) * WIDTH + h * 64 + pf_d;
    pk = *(const f32x2*)&Kb[a0];
    pq = *(const f32x2*)&Qb[a0];
    pv = *(const f32x2*)&Vb[a0];
    if (tid < 16) plr = LRb[(long)bh * 2048 + tid];
  }

  for (int n = 0; n < NCHUNK; ++n) {
    const long gbase = ((long)(b * LLL + n * MBSZ)) * WIDTH + h * 64;

    {
      *(unsigned*)&sX1b[pf_i * 72 + pf_d] = cvt_pk(pk[0], pk[1]);
      *(unsigned*)&sXQb[pf_i * 72 + pf_d] = cvt_pk(pq[0], pq[1]);
      sXQf[pf_i * 68 + pf_d] = pq[0];
      sXQf[pf_i * 68 + pf_d + 1] = pq[1];
      sTg[pf_i * 72 + pf_d] = pv[0] - pk[0];
      sTg[pf_i * 72 + pf_d + 1] = pv[1] - pk[1];
      if (tid < 16) sLr[tid] = plr;
    }
    __syncthreads();  // A

    short8 aX1[2], aXQ[2];
    aX1[0] = *(const short8*)&sX1b[fr * 72 + hk];
    aX1[1] = *(const short8*)&sX1b[fr * 72 + 32 + hk];
    aXQ[0] = *(const short8*)&sXQb[fr * 72 + hk];
    aXQ[1] = *(const short8*)&sXQb[fr * 72 + 32 + hk];
    f32x4 z1[2], q1[2];
    float b1p[2];
#pragma unroll
    for (int t = 0; t < 2; ++t) {
      const int p = (nt0 + t) * 16 + fr;
      z1[t] = zf4; q1[t] = zf4;
#pragma unroll
      for (int ks = 0; ks < 2; ++ks) {
        short8 bw = *(const short8*)&sW1b[p * 72 + ks * 32 + hk];
        z1[t] = MFMA16(aX1[ks], bw, z1[t]);
        q1[t] = MFMA16(aXQ[ks], bw, q1[t]);
      }
      b1p[t] = sB1[p];
#pragma unroll
      for (int qq = 0; qq < 4; ++qq) {
        z1[t][qq] += b1p[t];
        sX2b[(half * 4 + qq) * 264 + p] = f2bf(gelu_f(z1[t][qq]));
      }
    }
    {
      const float tok15 = sTok[15];
      const int d = tid >> 3, j0 = (tid & 7) * 2;
      const float v0 = bf2f(sX1b[j0 * 72 + d]) * (tok15 * sLr[j0]);
      const float v1 = bf2f(sX1b[(j0 + 1) * 72 + d]) * (tok15 * sLr[j0 + 1]);
      *(unsigned*)&la1T[d * 24 + j0] = cvt_pk(v0, v1);
    }
    if (w == 0) {
      f32x4 c = MFMA16(aXQ[0], aX1[0], zf4);
      c = MFMA16(aXQ[1], aX1[1], c);
#pragma unroll
      for (int qq = 0; qq < 4; ++qq) {
        const int i = half * 4 + qq, j = fr;
        sC1b[i * 24 + j] = f2bf((i >= j) ? sTok[i] * sLr[j] * (c[qq] + 1.0f) : 0.0f);
      }
    }
    __syncthreads();  // B

    float bb2old = 0.f;
    if (w < 4) {
      const int d = w * 16 + fr;
      const int sw = ((d >> 3) & 3) << 3;
      const int rb = w2row(d);
      f32x4 za = zf4, zb = zf4;
#pragma unroll
      for (int ks = 0; ks < 4; ++ks) {
        short8 a = *(const short8*)&sX2b[fr * 264 + ks * 32 + hk];
        short8 bfr = *(const short8*)&sW2dp[rb + ((ks * 32 + hk) ^ sw)];
        za = MFMA16(a, bfr, za);
      }
#pragma unroll
      for (int ks = 4; ks < 8; ++ks) {
        short8 a = *(const short8*)&sX2b[fr * 264 + ks * 32 + hk];
        short8 bfr = *(const short8*)&sW2dp[rb + ((ks * 32 + hk) ^ sw)];
        zb = MFMA16(a, bfr, zb);
      }
      bb2old = sB2[d];
#pragma unroll
      for (int qq = 0; qq < 4; ++qq)
        sZ2f[(half * 4 + qq) * 68 + d] = za[qq] + zb[qq] + bb2old;
    }
    __syncthreads();  // C

    if (tid < 256) {
      const int i = tid >> 4, j4 = tid & 15;
      const f32x4 z = *(const f32x4*)&sZ2f[i * 68 + j4 * 4];
      float s1 = z[0] + z[1] + z[2] + z[3];
      float s2 = z[0] * z[0] + z[1] * z[1] + z[2] * z[2] + z[3] * z[3];
#pragma unroll
      for (int o = 8; o; o >>= 1) { s1 += __shfl_xor(s1, o, 16); s2 += __shfl_xor(s2, o, 16); }
      const float mu = s1 * (1.f / 64.f);
      const float rstd = rsqrtf(s2 * (1.f / 64.f) - mu * mu + 1e-6f);
      const f32x4 g = *(const f32x4*)&sLnw[j4 * 4];
      const f32x4 bb = *(const f32x4*)&sLnb[j4 * 4];
      const f32x4 tg = *(const f32x4*)&sTg[i * 72 + j4 * 4];
      f32x4 xh, gx;
      float a1 = 0.f, a2 = 0.f;
#pragma unroll
      for (int e = 0; e < 4; ++e) {
        xh[e] = (z[e] - mu) * rstd;
        gx[e] = (g[e] * xh[e] + bb[e] - tg[e]) * g[e];
        a1 += gx[e]; a2 += gx[e] * xh[e];
      }
#pragma unroll
      for (int o = 8; o; o >>= 1) { a1 += __shfl_xor(a1, o, 16); a2 += __shfl_xor(a2, o, 16); }
      const float m1 = a1 * (1.f / 64.f), m2 = a2 * (1.f / 64.f);
      float o4[4];
#pragma unroll
      for (int e = 0; e < 4; ++e) o4[e] = (gx[e] - m1 - xh[e] * m2) * rstd;
      const unsigned lo = cvt_pk(o4[0], o4[1]);
      const unsigned hi = cvt_pk(o4[2], o4[3]);
      *(u32x2*)&sG2b[i * 72 + j4 * 4] = (u32x2){lo, hi};
      sG2c[(j4 * 4 + 0) * 24 + i] = (short)lo;
      sG2c[(j4 * 4 + 1) * 24 + i] = (short)(lo >> 16);
      sG2c[(j4 * 4 + 2) * 24 + i] = (short)hi;
      sG2c[(j4 * 4 + 3) * 24 + i] = (short)(hi >> 16);
    } else {
      const int pp = tid - 256;
      const float tok15 = sTok[15];
      unsigned uu[8];
#pragma unroll
      for (int jp = 0; jp < 8; ++jp) {
        const float v0 = bf2f(sX2b[(2 * jp) * 264 + pp]) * (tok15 * sLr[2 * jp]);
        const float v1 = bf2f(sX2b[(2 * jp + 1) * 264 + pp]) * (tok15 * sLr[2 * jp + 1]);
        uu[jp] = cvt_pk(v0, v1);
      }
      *(u32x4*)&la2T[pp * 24] = (u32x4){uu[0], uu[1], uu[2], uu[3]};
      *(u32x4*)&la2T[pp * 24 + 8] = (u32x4){uu[4], uu[5], uu[6], uu[7]};
    }
    __syncthreads();  // D

    {
      short8 aG2[2];
      aG2[0] = *(const short8*)&sG2b[fr * 72 + hk];
      aG2[1] = *(const short8*)&sG2b[fr * 72 + 32 + hk];
#pragma unroll
      for (int t = 0; t < 2; ++t) {
        const int p = (nt0 + t) * 16 + fr;
        f32x4 g = zf4;
#pragma unroll
        for (int ks = 0; ks < 2; ++ks) {
          const int dg = ks * 32 + hk;
          const int rb2 = w2row(dg) + (p ^ (((dg >> 3) & 3) << 3));
          short8 bw;
#pragma unroll
          for (int jj = 0; jj < 8; ++jj) bw[jj] = sW2dp[rb2 + jj * 264];
          g = MFMA16(aG2[ks], bw, g);
        }
        const unsigned lo = cvt_pk(g[0] * gelu_bwd_f(z1[t][0]), g[1] * gelu_bwd_f(z1[t][1]));
        const unsigned hi = cvt_pk(g[2] * gelu_bwd_f(z1[t][2]), g[3] * gelu_bwd_f(z1[t][3]));
        *(u32x2*)&sG1c[p * 24 + half * 4] = (u32x2){lo, hi};
      }
    }
    if (tid < 64) {
      float s = 0.f;
#pragma unroll
      for (int k = 0; k < 4; ++k) {
        const short4v g4 = *(const short4v*)&sG2c[tid * 24 + k * 4];
        const f32x4 lr4 = *(const f32x4*)&sLr[k * 4];
        s += lr4[0] * bf2f(g4[0]) + lr4[1] * bf2f(g4[1]) +
             lr4[2] * bf2f(g4[2]) + lr4[3] * bf2f(g4[3]);
      }
      sB2[tid] -= sTok[15] * s;
    }
    __syncthreads();  // E

    {
      short8 ac = zs8;
      if (half < 2) ac = *(const short8*)&sC1b[fr * 24 + hk];
#pragma unroll
      for (int t = 0; t < 2; ++t) {
        const int p = (nt0 + t) * 16 + fr;
        short8 bg = zs8;
        if (half < 2) bg = *(const short8*)&sG1c[p * 24 + hk];
        f32x4 corr = MFMA16(ac, bg, zf4);
#pragma unroll
        for (int qq = 0; qq < 4; ++qq)
          sXbb[(half * 4 + qq) * 264 + p] = f2bf(gelu_f(q1[t][qq] + b1p[t] - corr[qq]));
      }
    }
    {
#pragma unroll
      for (int r = 0; r < 8; ++r) {
        const int T = w * 8 + r, dt = T >> 4, pt = T & 15;
        short8 af = zs8, bg = zs8;
        if (half < 2) {
          af = *(const short8*)&la1T[(dt * 16 + fr) * 24 + hk];
          bg = *(const short8*)&sG1c[(pt * 16 + fr) * 24 + hk];
        }
        f32x4 dl = MFMA16(af, bg, zf4);
        const int pp = pt * 16 + fr, d0 = dt * 16 + half * 4;
        w1m[r][0] -= dl[0]; w1m[r][1] -= dl[1]; w1m[r][2] -= dl[2]; w1m[r][3] -= dl[3];
        const unsigned lo = cvt_pk(w1m[r][0], w1m[r][1]);
        const unsigned hi = cvt_pk(w1m[r][2], w1m[r][3]);
        *(u32x2*)&sW1b[pp * 72 + d0] = (u32x2){lo, hi};
      }
    }
    if (tid < 256) {
      float s = 0.f;
#pragma unroll
      for (int k = 0; k < 4; ++k) {
        const short4v g4 = *(const short4v*)&sG1c[tid * 24 + k * 4];
        const f32x4 lr4 = *(const f32x4*)&sLr[k * 4];
        s += lr4[0] * bf2f(g4[0]) + lr4[1] * bf2f(g4[1]) +
             lr4[2] * bf2f(g4[2]) + lr4[3] * bf2f(g4[3]);
      }
      sB1[tid] -= sTok[15] * s;
    }
    __syncthreads();  // F

    {
      const int nn = (n + 1 < NCHUNK) ? n + 1 : n;
      const long a1 = ((long)(b * LLL + nn * MBSZ + pf_i)) * WIDTH + h * 64 + pf_d;
      pk = *(const f32x2*)&Kb[a1];
      pq = *(const f32x2*)&Qb[a1];
      pv = *(const f32x2*)&Vb[a1];
      if (tid < 16) plr = LRb[(long)bh * 2048 + nn * MBSZ + tid];
    }
    f32x4 zbar = zf4;
    if (w < 4) {
      const int d = w * 16 + fr;
      const int sw = ((d >> 3) & 3) << 3;
      const int rb = w2row(d);
      f32x4 za = zf4, zb = zf4;
#pragma unroll
      for (int ks = 0; ks < 4; ++ks) {
        short8 a = *(const short8*)&sXbb[fr * 264 + ks * 32 + hk];
        short8 bfr = *(const short8*)&sW2dp[rb + ((ks * 32 + hk) ^ sw)];
        za = MFMA16(a, bfr, za);
      }
#pragma unroll
      for (int ks = 4; ks < 8; ++ks) {
        short8 a = *(const short8*)&sXbb[fr * 264 + ks * 32 + hk];
        short8 bfr = *(const short8*)&sW2dp[rb + ((ks * 32 + hk) ^ sw)];
        zb = MFMA16(a, bfr, zb);
      }
      zbar[0] = za[0] + zb[0]; zbar[1] = za[1] + zb[1];
      zbar[2] = za[2] + zb[2]; zbar[3] = za[3] + zb[3];
    } else if (w == 4) {
      f32x4 c = zf4;
#pragma unroll
      for (int ks = 0; ks < 8; ++ks) {
        short8 a = *(const short8*)&sXbb[fr * 264 + ks * 32 + hk];
        short8 bx = *(const short8*)&sX2b[fr * 264 + ks * 32 + hk];
        c = MFMA16(a, bx, c);
      }
#pragma unroll
      for (int qq = 0; qq < 4; ++qq) {
        const int i = half * 4 + qq, j = fr;
        sC2b[i * 24 + j] = f2bf((i >= j) ? sTok[i] * sLr[j] * (c[qq] + 1.0f) : 0.0f);
      }
    }
    __syncthreads();  // G

    if (w < 4) {
      const int d = w * 16 + fr;
      short8 ac = zs8, bg = zs8;
      if (half < 2) {
        ac = *(const short8*)&sC2b[fr * 24 + hk];
        bg = *(const short8*)&sG2c[d * 24 + hk];
      }
      f32x4 corr = MFMA16(ac, bg, zf4);
#pragma unroll
      for (int qq = 0; qq < 4; ++qq)
        sZ2f[(half * 4 + qq) * 68 + d] = zbar[qq] + bb2old - corr[qq];
    }
    {
#pragma unroll
      for (int r = 0; r < 8; ++r) {
        const int T = w * 8 + r, pt = T & 15, dt = T >> 4;
        short8 af = zs8, bg = zs8;
        if (half < 2) {
          af = *(const short8*)&la2T[(pt * 16 + fr) * 24 + hk];
          bg = *(const short8*)&sG2c[(dt * 16 + fr) * 24 + hk];
        }
        f32x4 dl = MFMA16(af, bg, zf4);
        const int dd = dt * 16 + fr;
        const int swp = ((dd >> 3) & 3) << 3;
        const int p0 = pt * 16 + half * 4;
        w2m[r][0] -= dl[0]; w2m[r][1] -= dl[1]; w2m[r][2] -= dl[2]; w2m[r][3] -= dl[3];
        const unsigned lo = cvt_pk(w2m[r][0], w2m[r][1]);
        const unsigned hi = cvt_pk(w2m[r][2], w2m[r][3]);
        *(u32x2*)&sW2dp[w2row(dd) + (p0 ^ swp)] = (u32x2){lo, hi};
      }
    }
    __syncthreads();  // H

    if (tid < 256) {
      const int i = tid >> 4, j4 = tid & 15;
      const f32x4 z = *(const f32x4*)&sZ2f[i * 68 + j4 * 4];
      float s1 = z[0] + z[1] + z[2] + z[3];
      float s2 = z[0] * z[0] + z[1] * z[1] + z[2] * z[2] + z[3] * z[3];
#pragma unroll
      for (int o = 8; o; o >>= 1) { s1 += __shfl_xor(s1, o, 16); s2 += __shfl_xor(s2, o, 16); }
      const float mu = s1 * (1.f / 64.f);
      const float rstd = rsqrtf(s2 * (1.f / 64.f) - mu * mu + 1e-6f);
      const f32x4 g = *(const f32x4*)&sLnw[j4 * 4];
      const f32x4 bb = *(const f32x4*)&sLnb[j4 * 4];
      const f32x4 xq = *(const f32x4*)&sXQf[i * 68 + j4 * 4];
      f32x4 o4;
#pragma unroll
      for (int e = 0; e < 4; ++e) o4[e] = xq[e] + g[e] * ((z[e] - mu) * rstd) + bb[e];
      *(f32x4*)&Qb[gbase + (long)i * WIDTH + j4 * 4] = o4;
    }
    __syncthreads();  // I
  }
}

// ---------------- epilogue: T(bf16) = gelu(G_bf16) * ln_fwd(XQW_f32, post_w, post_b)
__global__ __launch_bounds__(256) void epi_kernel(const float* __restrict__ X,
                                                  const short* __restrict__ G,
                                                  const float* __restrict__ pw,
                                                  const float* __restrict__ pb,
                                                  short* __restrict__ T) {
  __shared__ float red[8];
  const int t = blockIdx.x, tid = threadIdx.x;
  const long base = (long)t * 1024 + tid * 4;
  f32x4 x = *(const f32x4*)&X[base];
  float s1 = x[0] + x[1] + x[2] + x[3];
  float s2 = x[0] * x[0] + x[1] * x[1] + x[2] * x[2] + x[3] * x[3];
#pragma unroll
  for (int o = 32; o; o >>= 1) { s1 += __shfl_xor(s1, o, 64); s2 += __shfl_xor(s2, o, 64); }
  const int wv = tid >> 6, ln = tid & 63;
  if (ln == 0) { red[wv] = s1; red[4 + wv] = s2; }
  __syncthreads();
  s1 = red[0] + red[1] + red[2] + red[3];
  s2 = red[4] + red[5] + red[6] + red[7];
  const float mu = s1 * (1.f / 1024.f);
  const float rstd = rsqrtf(s2 * (1.f / 1024.f) - mu * mu + 1e-6f);
  const short4v g4 = *(const short4v*)&G[base];
  f32x4 w = *(const f32x4*)&pw[tid * 4];
  f32x4 bb = *(const f32x4*)&pb[tid * 4];
  float o4[4];
#pragma unroll
  for (int e = 0; e < 4; ++e) {
    float y = w[e] * ((x[e] - mu) * rstd) + bb[e];
    o4[e] = gelu_f(bf2f(g4[e])) * y;
  }
  *(u32x2*)&T[base] = (u32x2){cvt_pk(o4[0], o4[1]), cvt_pk(o4[2], o4[3])};
}

extern "C" void kernel_launch(void* const* d_in, const int* in_sizes, int n_in,
                              void* d_out, int out_size, void* d_ws, size_t ws_size,
                              hipStream_t stream) {
  const float* hs  = (const float*)d_in[0];
  const float* Wq  = (const float*)d_in[1];
  const float* Wk  = (const float*)d_in[2];
  const float* Wv  = (const float*)d_in[3];
  const float* Wo  = (const float*)d_in[4];
  const float* Wg  = (const float*)d_in[5];
  const float* lrw = (const float*)d_in[6];
  const float* lrb = (const float*)d_in[7];
  const float* lti = (const float*)d_in[8];
  const float* nw  = (const float*)d_in[9];
  const float* nb  = (const float*)d_in[10];
  const float* W1  = (const float*)d_in[11];
  const float* b1  = (const float*)d_in[12];
  const float* W2  = (const float*)d_in[13];
  const float* b2  = (const float*)d_in[14];
  const float* pw  = (const float*)d_in[15];
  const float* pb  = (const float*)d_in[16];
  float* out = (float*)d_out;
  float* ws = (float*)d_ws;

  float* Qb  = ws;                       // 8M f32
  float* Kb  = ws + 8388608;             // 8M f32 (T bf16 overlays after scan)
  float* Vb  = ws + 16777216;            // 8M f32
  float* LRb = ws + 25165824;            // 131072 f32
  short* hsb = (short*)(ws + 25296896);  // 8M bf16
  short* Wqb = hsb + 8388608;
  short* Wkb = Wqb + 1048576;
  short* Wvb = Wkb + 1048576;
  short* Wgb = Wvb + 1048576;
  short* Wob = Wgb + 1048576;
  short* Tb  = (short*)Kb;
  short* Gbb = (short*)out;              // gate bf16 lives in d_out (dead until final GEMM)

  cvt_kernel<<<6656, 256, 0, stream>>>(hs, Wq, Wk, Wv, Wg, Wo, hsb);
  qkv_lr_kernel<<<11264, 256, 0, stream>>>(hsb, Wqb, Wkb, Wvb, Qb, Kb, Vb, hs, lrw, lrb, LRb);
  scan_gate_kernel<<<576, 512, 0, stream>>>(Qb, Kb, Vb, LRb, lti, nw, nb, W1, b1, W2, b2,
                                            hsb, Wgb, Gbb);
  epi_kernel<<<8192, 256, 0, stream>>>(Qb, Gbb, pw, pb, Tb);
  gemm_final<<<dim3(128, 8), 256, 0, stream>>>(Tb, Wob, out);
}